// Round 5
// baseline (197.396 us; speedup 1.0000x reference)
//
#include <hip/hip_runtime.h>
#include <math.h>

#define BB 4
#define CIN 128
#define LL 2048
#define HH 8
#define CH 32
#define HID 256

typedef __attribute__((ext_vector_type(8))) __bf16 bf16x8;
typedef __attribute__((ext_vector_type(4))) float f32x4;

static __device__ __forceinline__ unsigned int f2bf(float f) {
    union { __bf16 b; unsigned short s; } u;
    u.b = (__bf16)f;
    return (unsigned int)u.s;
}
static __device__ __forceinline__ float bf2f(unsigned int s) {
    union { float f; unsigned int u; } x;
    x.u = s << 16;
    return x.f;
}

// ---------------------------------------------------------------------------
// Kernel 1: QKV 1x1 conv -> bf16 buffers.
// Q: [bh][l][d] bf16, pre-scaled by log2(e)/sqrt(L) (so exp(s) == exp2(s')).
// K: [bh][l][d] bf16.  V: transposed [bh][d][l] bf16.
// ---------------------------------------------------------------------------
__global__ __launch_bounds__(256) void qkv_kernel(
        const float* __restrict__ x, const float* __restrict__ w_qkv,
        const float* __restrict__ b_qkv,
        unsigned short* __restrict__ qb, unsigned short* __restrict__ kb,
        unsigned short* __restrict__ vtb) {
    __shared__ float wl[32 * 128];
    __shared__ float tr[32 * 65];
    const int t = threadIdx.x;
    const int lt = blockIdx.x;           // 0..31
    const int g  = blockIdx.y;           // 0..23 : sel*8 + h
    const int b  = blockIdx.z;
    const int sel = g >> 3, h = g & 7;
    const int obase = sel * 256 + h * 32;
    const int l0 = lt * 64;

    const float4* wsrc = (const float4*)(w_qkv + (size_t)obase * CIN);
    float4* wdst = (float4*)wl;
    #pragma unroll
    for (int r = 0; r < 4; ++r) wdst[r * 256 + t] = wsrc[r * 256 + t];
    __syncthreads();

    const int ll = t & 63, og = t >> 6;
    float acc[8] = {0.f,0.f,0.f,0.f,0.f,0.f,0.f,0.f};
    const float* xp = x + (size_t)b * CIN * LL + l0 + ll;
    for (int i = 0; i < CIN; i += 4) {
        float x0 = xp[(size_t)(i+0) * LL];
        float x1 = xp[(size_t)(i+1) * LL];
        float x2 = xp[(size_t)(i+2) * LL];
        float x3 = xp[(size_t)(i+3) * LL];
        #pragma unroll
        for (int j = 0; j < 8; ++j) {
            float4 w4 = *(const float4*)(wl + (og * 8 + j) * 128 + i);
            acc[j] += w4.x * x0 + w4.y * x1 + w4.z * x2 + w4.w * x3;
        }
    }
    // log2(e)/sqrt(2048)
    const float scale = (sel == 0) ? 0.03187935835f : 1.0f;
    #pragma unroll
    for (int j = 0; j < 8; ++j) {
        int oc = og * 8 + j;
        tr[oc * 65 + ll] = (acc[j] + b_qkv[obase + oc]) * scale;   // [c][l]
    }
    __syncthreads();
    if (sel == 2) {
        unsigned short* dst = vtb + ((size_t)(b * HH + h) * CH) * LL + l0;
        #pragma unroll
        for (int r = 0; r < 8; ++r) {
            int flat = r * 256 + t;           // c*64 + l
            int c = flat >> 6, l = flat & 63;
            dst[(size_t)c * LL + l] = (unsigned short)f2bf(tr[c * 65 + l]);
        }
    } else {
        unsigned short* dst = (sel == 0 ? qb : kb)
                              + ((size_t)(b * HH + h) * LL + l0) * CH;
        #pragma unroll
        for (int r = 0; r < 8; ++r) {
            int flat = r * 256 + t;           // lr*32 + c
            int c = flat & 31, lr = flat >> 5;
            dst[flat] = (unsigned short)f2bf(tr[c * 65 + lr]);
        }
    }
}

// ---------------------------------------------------------------------------
// Kernel 2: softmax denominators via MFMA, then scale V^T in place.
// 512 threads: waves 0-3 sum a in [0,1024), waves 4-7 in [1024,2048);
// LDS-combine, then vtb[bh][d][q] *= 1/z[q].
// ---------------------------------------------------------------------------
__global__ __launch_bounds__(512) void denom_mfma(
        const unsigned short* __restrict__ qb,
        const unsigned short* __restrict__ kb,
        unsigned short* __restrict__ vtb) {
    __shared__ float zz[2][64];
    const int t = threadIdx.x, wave = t >> 6, lane = t & 63;
    const int id = blockIdx.x;
    const int bh = (id & 7) * 4 + ((id >> 3) >> 5);
    const int qt = (id >> 3) & 31;
    const int ah = wave >> 2, wsub = wave & 3;
    const int q0 = qt * 64 + wsub * 16;
    const int r = lane & 15, g = lane >> 4;

    bf16x8 afrag = *(const bf16x8*)(qb + ((size_t)bh * LL + q0 + r) * CH + 8 * g);
    const unsigned short* kp = kb + ((size_t)bh * LL + r) * CH + 8 * g;

    float z0 = 0.f, z1 = 0.f, z2 = 0.f, z3 = 0.f;
    const f32x4 zero = {0.f, 0.f, 0.f, 0.f};
    for (int a0 = ah * 1024; a0 < ah * 1024 + 1024; a0 += 64) {
        #pragma unroll
        for (int s = 0; s < 4; ++s) {
            bf16x8 bfrag = *(const bf16x8*)(kp + (size_t)(a0 + s * 16) * CH);
            f32x4 d = __builtin_amdgcn_mfma_f32_16x16x32_bf16(afrag, bfrag, zero, 0, 0, 0);
            z0 += __builtin_amdgcn_exp2f(d[0]);
            z1 += __builtin_amdgcn_exp2f(d[1]);
            z2 += __builtin_amdgcn_exp2f(d[2]);
            z3 += __builtin_amdgcn_exp2f(d[3]);
        }
    }
    #pragma unroll
    for (int m = 1; m < 16; m <<= 1) {
        z0 += __shfl_xor(z0, m); z1 += __shfl_xor(z1, m);
        z2 += __shfl_xor(z2, m); z3 += __shfl_xor(z3, m);
    }
    if (r == 0) {
        *(float4*)&zz[ah][wsub * 16 + 4 * g] = make_float4(z0, z1, z2, z3);
    }
    __syncthreads();

    // scale vtb[bh][d][qt*64 .. +63]: 512 thr x 4 elems = 32 d x 64 q
    const int d = t >> 4, qo = (t & 15) * 4;
    const float i0 = 1.f / (zz[0][qo + 0] + zz[1][qo + 0]);
    const float i1 = 1.f / (zz[0][qo + 1] + zz[1][qo + 1]);
    const float i2 = 1.f / (zz[0][qo + 2] + zz[1][qo + 2]);
    const float i3 = 1.f / (zz[0][qo + 3] + zz[1][qo + 3]);
    unsigned short* vrow = vtb + ((size_t)bh * CH + d) * LL + qt * 64 + qo;
    uint2 v = *(const uint2*)vrow;
    unsigned int w0, w1;
    w0 = f2bf(bf2f(v.x & 0xFFFFu) * i0) | (f2bf(bf2f(v.x >> 16) * i1) << 16);
    w1 = f2bf(bf2f(v.y & 0xFFFFu) * i2) | (f2bf(bf2f(v.y >> 16) * i3) << 16);
    *(uint2*)vrow = make_uint2(w0, w1);
}

// ---------------------------------------------------------------------------
// Kernel 3: attn^T via MFMA, software-pipelined per-wave LDS P^T bounce.
// q split into 4 quarters (qq); partial sums stored as bf16.
// attnT[qq][b][h*32+d][a] = sum_{q in quarter} exp2(s') V'[q,d]
// ---------------------------------------------------------------------------
__global__ __launch_bounds__(256, 8) void attn_mfma(
        const unsigned short* __restrict__ qb,
        const unsigned short* __restrict__ kb,
        const unsigned short* __restrict__ vtb,
        unsigned short* __restrict__ attnT) {
    __shared__ unsigned short ptA[4][32][36];   // per-wave P^T, stride 36 (72B)
    __shared__ unsigned short ptB[4][32][36];
    const int t = threadIdx.x, wave = t >> 6, lane = t & 63;
    const int r = lane & 15, g = lane >> 4;
    const int id = blockIdx.x;                   // 0..2047
    const int rest = id >> 3;                    // 0..255
    const int bh = (id & 7) * 4 + (rest >> 6);
    const int mid = rest & 63;
    const int qq = mid & 3, at = mid >> 2;       // qq 0..3, at 0..15
    const int b = bh >> 3, h = bh & 7;
    const int a0 = at * 128 + wave * 32;
    const int q00 = qq * 512;

    const unsigned short* kp = kb + ((size_t)bh * LL + a0 + r) * CH + 8 * g;
    const bf16x8 kf0 = *(const bf16x8*)kp;
    const bf16x8 kf1 = *(const bf16x8*)(kp + 16 * CH);
    const unsigned short* qp  = qb  + ((size_t)bh * LL + q00 + r) * CH + 8 * g;
    const unsigned short* vp0 = vtb + ((size_t)bh * CH + r) * LL + q00 + 8 * g;
    const unsigned short* vp1 = vp0 + (size_t)16 * LL;

    unsigned short* const bA = &ptA[wave][0][0];
    unsigned short* const bB = &ptB[wave][0][0];
    const int rd0 = r * 36 + 8 * g, rd1 = rd0 + 576;
    const int wr0 = r * 36 + 4 * g, wr1 = wr0 + 576;

    f32x4 acc00 = {0,0,0,0}, acc01 = {0,0,0,0}, acc10 = {0,0,0,0}, acc11 = {0,0,0,0};
    const f32x4 zero = {0.f, 0.f, 0.f, 0.f};

#define E2(x) __builtin_amdgcn_exp2f(x)
#define PACK2(s) make_uint2( \
        f2bf(E2((s)[0])) | (f2bf(E2((s)[1])) << 16), \
        f2bf(E2((s)[2])) | (f2bf(E2((s)[3])) << 16))

    // ---- prologue: compute & store P(0), prefetch q(1), load v(0) ----
    bf16x8 qn0 = *(const bf16x8*)qp;
    bf16x8 qn1 = *(const bf16x8*)(qp + 16 * CH);
    {
        f32x4 s00 = __builtin_amdgcn_mfma_f32_16x16x32_bf16(qn0, kf0, zero, 0, 0, 0);
        f32x4 s01 = __builtin_amdgcn_mfma_f32_16x16x32_bf16(qn0, kf1, zero, 0, 0, 0);
        f32x4 s10 = __builtin_amdgcn_mfma_f32_16x16x32_bf16(qn1, kf0, zero, 0, 0, 0);
        f32x4 s11 = __builtin_amdgcn_mfma_f32_16x16x32_bf16(qn1, kf1, zero, 0, 0, 0);
        *(uint2*)(bA + wr0)      = PACK2(s00);
        *(uint2*)(bA + wr1)      = PACK2(s01);
        *(uint2*)(bA + wr0 + 16) = PACK2(s10);
        *(uint2*)(bA + wr1 + 16) = PACK2(s11);
    }
    bf16x8 vc0 = *(const bf16x8*)vp0;
    bf16x8 vc1 = *(const bf16x8*)vp1;
    qn0 = *(const bf16x8*)(qp + 32 * CH);
    qn1 = *(const bf16x8*)(qp + 48 * CH);
    const unsigned short* qpn  = qp + 64 * CH;   // q frags for stage n+2
    const unsigned short* vpn0 = vp0 + 32;       // v frags for stage n+1
    const unsigned short* vpn1 = vp1 + 32;

#define STAGE(RD, WR, DOS, DOQ, DOV) do { \
    bf16x8 pa0 = *(const bf16x8*)((RD) + rd0); \
    bf16x8 pa1 = *(const bf16x8*)((RD) + rd1); \
    if (DOS) { \
        f32x4 s00 = __builtin_amdgcn_mfma_f32_16x16x32_bf16(qn0, kf0, zero, 0, 0, 0); \
        f32x4 s01 = __builtin_amdgcn_mfma_f32_16x16x32_bf16(qn0, kf1, zero, 0, 0, 0); \
        f32x4 s10 = __builtin_amdgcn_mfma_f32_16x16x32_bf16(qn1, kf0, zero, 0, 0, 0); \
        f32x4 s11 = __builtin_amdgcn_mfma_f32_16x16x32_bf16(qn1, kf1, zero, 0, 0, 0); \
        *(uint2*)((WR) + wr0)      = PACK2(s00); \
        *(uint2*)((WR) + wr1)      = PACK2(s01); \
        *(uint2*)((WR) + wr0 + 16) = PACK2(s10); \
        *(uint2*)((WR) + wr1 + 16) = PACK2(s11); \
    } \
    if (DOQ) { \
        qn0 = *(const bf16x8*)qpn; \
        qn1 = *(const bf16x8*)(qpn + 16 * CH); \
        qpn += 32 * CH; \
    } \
    __builtin_amdgcn_s_setprio(1); \
    acc00 = __builtin_amdgcn_mfma_f32_16x16x32_bf16(pa0, vc0, acc00, 0, 0, 0); \
    acc01 = __builtin_amdgcn_mfma_f32_16x16x32_bf16(pa0, vc1, acc01, 0, 0, 0); \
    acc10 = __builtin_amdgcn_mfma_f32_16x16x32_bf16(pa1, vc0, acc10, 0, 0, 0); \
    acc11 = __builtin_amdgcn_mfma_f32_16x16x32_bf16(pa1, vc1, acc11, 0, 0, 0); \
    __builtin_amdgcn_s_setprio(0); \
    if (DOV) { \
        vc0 = *(const bf16x8*)vpn0; \
        vc1 = *(const bf16x8*)vpn1; \
        vpn0 += 32; vpn1 += 32; \
    } \
} while (0)

    for (int nn = 0; nn < 7; ++nn) {
        STAGE(bA, bB, 1, 1, 1);    // stage 2nn
        STAGE(bB, bA, 1, 1, 1);    // stage 2nn+1
    }
    STAGE(bA, bB, 1, 0, 1);        // stage 14: compute/write P(15), load v(15)
    STAGE(bB, bA, 0, 0, 0);        // stage 15: PV only

#undef STAGE
#undef PACK2
#undef E2

    // bf16 partial store
    unsigned short* ob = attnT + ((size_t)(qq * BB + b) * HID + h * CH) * LL;
    {
        uint2 u;
        u = make_uint2(f2bf(acc00[0]) | (f2bf(acc00[1]) << 16),
                       f2bf(acc00[2]) | (f2bf(acc00[3]) << 16));
        *(uint2*)(ob + (size_t)(r     ) * LL + a0 +      4 * g) = u;
        u = make_uint2(f2bf(acc01[0]) | (f2bf(acc01[1]) << 16),
                       f2bf(acc01[2]) | (f2bf(acc01[3]) << 16));
        *(uint2*)(ob + (size_t)(16 + r) * LL + a0 +      4 * g) = u;
        u = make_uint2(f2bf(acc10[0]) | (f2bf(acc10[1]) << 16),
                       f2bf(acc10[2]) | (f2bf(acc10[3]) << 16));
        *(uint2*)(ob + (size_t)(r     ) * LL + a0 + 16 + 4 * g) = u;
        u = make_uint2(f2bf(acc11[0]) | (f2bf(acc11[1]) << 16),
                       f2bf(acc11[2]) | (f2bf(acc11[3]) << 16));
        *(uint2*)(ob + (size_t)(16 + r) * LL + a0 + 16 + 4 * g) = u;
    }
}

// ---------------------------------------------------------------------------
// Kernel 4: out[b,o,l] = BN( w_out @ (sum of 4 bf16 partials) + b_out + x )
// Thread handles 2 adjacent l (uint loads of bf16 pairs).
// ---------------------------------------------------------------------------
__global__ __launch_bounds__(256) void out_kernel(
        const unsigned short* __restrict__ attnT, const float* __restrict__ x,
        const float* __restrict__ w_out, const float* __restrict__ b_out,
        const float* __restrict__ bnw, const float* __restrict__ bnb,
        const float* __restrict__ bnm, const float* __restrict__ bnv,
        float* __restrict__ out) {
    __shared__ float wl[8 * 256];
    const int t = threadIdx.x;
    const int l0 = blockIdx.x * 512;
    const int o0 = blockIdx.y * 8;
    const int b  = blockIdx.z;

    const float4* ws = (const float4*)(w_out + (size_t)o0 * HID);
    float4* wd = (float4*)wl;
    #pragma unroll
    for (int r = 0; r < 2; ++r) wd[r * 256 + t] = ws[r * 256 + t];
    __syncthreads();

    float acc[8][2];
    #pragma unroll
    for (int j = 0; j < 8; ++j) { acc[j][0] = 0.f; acc[j][1] = 0.f; }

    const size_t PART = (size_t)BB * HID * LL;
    const unsigned short* ap = attnT + (size_t)b * HID * LL + l0 + 2 * t;
    for (int i = 0; i < HID; ++i) {
        float a0 = 0.f, a1 = 0.f;
        #pragma unroll
        for (int p = 0; p < 4; ++p) {
            unsigned int u = *(const unsigned int*)(ap + p * PART + (size_t)i * LL);
            a0 += bf2f(u & 0xFFFFu);
            a1 += bf2f(u >> 16);
        }
        #pragma unroll
        for (int j = 0; j < 8; ++j) {
            float w = wl[j * 256 + i];
            acc[j][0] += w * a0;
            acc[j][1] += w * a1;
        }
    }
    #pragma unroll
    for (int j = 0; j < 8; ++j) {
        const int o = o0 + j;
        const float inv = bnw[o] / sqrtf(bnv[o] + 1e-5f);
        const float sh  = bnb[o] - bnm[o] * inv;
        const size_t idx = ((size_t)b * CIN + o) * LL + l0 + 2 * t;
        float2 xx = *(const float2*)(x + idx);
        float2 ov;
        ov.x = (acc[j][0] + b_out[o] + xx.x) * inv + sh;
        ov.y = (acc[j][1] + b_out[o] + xx.y) * inv + sh;
        *(float2*)(out + idx) = ov;
    }
}

// ---------------------------------------------------------------------------
extern "C" void kernel_launch(void* const* d_in, const int* in_sizes, int n_in,
                              void* d_out, int out_size, void* d_ws, size_t ws_size,
                              hipStream_t stream) {
    const float* x      = (const float*)d_in[0];
    const float* w_qkv  = (const float*)d_in[1];
    const float* b_qkv  = (const float*)d_in[2];
    const float* w_out  = (const float*)d_in[3];
    const float* b_out  = (const float*)d_in[4];
    const float* bnw    = (const float*)d_in[5];
    const float* bnb    = (const float*)d_in[6];
    const float* bnm    = (const float*)d_in[7];
    const float* bnv    = (const float*)d_in[8];
    float* out = (float*)d_out;

    const size_t NBH = (size_t)BB * HH;          // 32
    const size_t QKV_ELEMS = NBH * LL * CH;      // 2,097,152 bf16 elems each
    unsigned short* qb    = (unsigned short*)d_ws;
    unsigned short* kb    = qb + QKV_ELEMS;
    unsigned short* vtb   = kb + QKV_ELEMS;
    unsigned short* attnT = vtb + QKV_ELEMS;     // 4 x 4 MB bf16 partials

    qkv_kernel<<<dim3(32, 24, BB), 256, 0, stream>>>(x, w_qkv, b_qkv, qb, kb, vtb);
    denom_mfma<<<dim3(1024), 512, 0, stream>>>(qb, kb, vtb);
    attn_mfma<<<dim3(2048), 256, 0, stream>>>(qb, kb, vtb, attnT);
    out_kernel<<<dim3(4, 16, BB), 256, 0, stream>>>(attnT, x, w_out, b_out,
                                                    bnw, bnb, bnm, bnv, out);
}

// Round 6
// 181.420 us; speedup vs baseline: 1.0881x; 1.0881x over previous
//
#include <hip/hip_runtime.h>
#include <math.h>

#define BB 4
#define CIN 128
#define LL 2048
#define HH 8
#define CH 32
#define HID 256

typedef __attribute__((ext_vector_type(8))) __bf16 bf16x8;
typedef __attribute__((ext_vector_type(4))) float f32x4;

static __device__ __forceinline__ unsigned int f2bf(float f) {
    union { __bf16 b; unsigned short s; } u;
    u.b = (__bf16)f;
    return (unsigned int)u.s;
}
static __device__ __forceinline__ float bf2f(unsigned int s) {
    union { float f; unsigned int u; } x;
    x.u = s << 16;
    return x.f;
}

// ---------------------------------------------------------------------------
// Kernel 1: QKV 1x1 conv -> bf16 buffers.
// Q: [bh][l][d] bf16, pre-scaled by log2(e)/sqrt(L) (so exp(s) == exp2(s')).
// K: [bh][l][d] bf16.  V: transposed [bh][d][l] bf16.
// ---------------------------------------------------------------------------
__global__ __launch_bounds__(256) void qkv_kernel(
        const float* __restrict__ x, const float* __restrict__ w_qkv,
        const float* __restrict__ b_qkv,
        unsigned short* __restrict__ qb, unsigned short* __restrict__ kb,
        unsigned short* __restrict__ vtb) {
    __shared__ float wl[32 * 128];
    __shared__ float tr[32 * 65];
    const int t = threadIdx.x;
    const int lt = blockIdx.x;           // 0..31
    const int g  = blockIdx.y;           // 0..23 : sel*8 + h
    const int b  = blockIdx.z;
    const int sel = g >> 3, h = g & 7;
    const int obase = sel * 256 + h * 32;
    const int l0 = lt * 64;

    const float4* wsrc = (const float4*)(w_qkv + (size_t)obase * CIN);
    float4* wdst = (float4*)wl;
    #pragma unroll
    for (int r = 0; r < 4; ++r) wdst[r * 256 + t] = wsrc[r * 256 + t];
    __syncthreads();

    const int ll = t & 63, og = t >> 6;
    float acc[8] = {0.f,0.f,0.f,0.f,0.f,0.f,0.f,0.f};
    const float* xp = x + (size_t)b * CIN * LL + l0 + ll;
    for (int i = 0; i < CIN; i += 4) {
        float x0 = xp[(size_t)(i+0) * LL];
        float x1 = xp[(size_t)(i+1) * LL];
        float x2 = xp[(size_t)(i+2) * LL];
        float x3 = xp[(size_t)(i+3) * LL];
        #pragma unroll
        for (int j = 0; j < 8; ++j) {
            float4 w4 = *(const float4*)(wl + (og * 8 + j) * 128 + i);
            acc[j] += w4.x * x0 + w4.y * x1 + w4.z * x2 + w4.w * x3;
        }
    }
    // log2(e)/sqrt(2048)
    const float scale = (sel == 0) ? 0.03187935835f : 1.0f;
    #pragma unroll
    for (int j = 0; j < 8; ++j) {
        int oc = og * 8 + j;
        tr[oc * 65 + ll] = (acc[j] + b_qkv[obase + oc]) * scale;   // [c][l]
    }
    __syncthreads();
    if (sel == 2) {
        unsigned short* dst = vtb + ((size_t)(b * HH + h) * CH) * LL + l0;
        #pragma unroll
        for (int r = 0; r < 8; ++r) {
            int flat = r * 256 + t;           // c*64 + l
            int c = flat >> 6, l = flat & 63;
            dst[(size_t)c * LL + l] = (unsigned short)f2bf(tr[c * 65 + l]);
        }
    } else {
        unsigned short* dst = (sel == 0 ? qb : kb)
                              + ((size_t)(b * HH + h) * LL + l0) * CH;
        #pragma unroll
        for (int r = 0; r < 8; ++r) {
            int flat = r * 256 + t;           // lr*32 + c
            int c = flat & 31, lr = flat >> 5;
            dst[flat] = (unsigned short)f2bf(tr[c * 65 + lr]);
        }
    }
}

// ---------------------------------------------------------------------------
// Kernel 2: softmax denominators via MFMA, then scale V^T in place.
// 512 threads: waves 0-3 sum a in [0,1024), waves 4-7 in [1024,2048);
// LDS-combine, then vtb[bh][d][q] *= 1/z[q].
// ---------------------------------------------------------------------------
__global__ __launch_bounds__(512) void denom_mfma(
        const unsigned short* __restrict__ qb,
        const unsigned short* __restrict__ kb,
        unsigned short* __restrict__ vtb) {
    __shared__ float zz[2][64];
    const int t = threadIdx.x, wave = t >> 6, lane = t & 63;
    const int id = blockIdx.x;
    const int bh = (id & 7) * 4 + ((id >> 3) >> 5);
    const int qt = (id >> 3) & 31;
    const int ah = wave >> 2, wsub = wave & 3;
    const int q0 = qt * 64 + wsub * 16;
    const int r = lane & 15, g = lane >> 4;

    bf16x8 afrag = *(const bf16x8*)(qb + ((size_t)bh * LL + q0 + r) * CH + 8 * g);
    const unsigned short* kp = kb + ((size_t)bh * LL + r) * CH + 8 * g;

    float z0 = 0.f, z1 = 0.f, z2 = 0.f, z3 = 0.f;
    const f32x4 zero = {0.f, 0.f, 0.f, 0.f};
    for (int a0 = ah * 1024; a0 < ah * 1024 + 1024; a0 += 64) {
        #pragma unroll
        for (int s = 0; s < 4; ++s) {
            bf16x8 bfrag = *(const bf16x8*)(kp + (size_t)(a0 + s * 16) * CH);
            f32x4 d = __builtin_amdgcn_mfma_f32_16x16x32_bf16(afrag, bfrag, zero, 0, 0, 0);
            z0 += __builtin_amdgcn_exp2f(d[0]);
            z1 += __builtin_amdgcn_exp2f(d[1]);
            z2 += __builtin_amdgcn_exp2f(d[2]);
            z3 += __builtin_amdgcn_exp2f(d[3]);
        }
    }
    #pragma unroll
    for (int m = 1; m < 16; m <<= 1) {
        z0 += __shfl_xor(z0, m); z1 += __shfl_xor(z1, m);
        z2 += __shfl_xor(z2, m); z3 += __shfl_xor(z3, m);
    }
    if (r == 0) {
        *(float4*)&zz[ah][wsub * 16 + 4 * g] = make_float4(z0, z1, z2, z3);
    }
    __syncthreads();

    // scale vtb[bh][d][qt*64 .. +63]: 512 thr x 4 elems = 32 d x 64 q
    const int d = t >> 4, qo = (t & 15) * 4;
    const float i0 = 1.f / (zz[0][qo + 0] + zz[1][qo + 0]);
    const float i1 = 1.f / (zz[0][qo + 1] + zz[1][qo + 1]);
    const float i2 = 1.f / (zz[0][qo + 2] + zz[1][qo + 2]);
    const float i3 = 1.f / (zz[0][qo + 3] + zz[1][qo + 3]);
    unsigned short* vrow = vtb + ((size_t)bh * CH + d) * LL + qt * 64 + qo;
    uint2 v = *(const uint2*)vrow;
    unsigned int w0, w1;
    w0 = f2bf(bf2f(v.x & 0xFFFFu) * i0) | (f2bf(bf2f(v.x >> 16) * i1) << 16);
    w1 = f2bf(bf2f(v.y & 0xFFFFu) * i2) | (f2bf(bf2f(v.y >> 16) * i3) << 16);
    *(uint2*)vrow = make_uint2(w0, w1);
}

// ---------------------------------------------------------------------------
// Kernel 3: attn^T via MFMA, software-pipelined per-wave LDS P^T bounce.
// q split into 4 quarters (qq); partial sums stored as f32 (full-sector
// 64B row coverage per store instruction -> no RFO amplification).
// attnT[qq][b][h*32+d][a] = sum_{q in quarter} exp2(s') V'[q,d]
// ---------------------------------------------------------------------------
__global__ __launch_bounds__(256, 8) void attn_mfma(
        const unsigned short* __restrict__ qb,
        const unsigned short* __restrict__ kb,
        const unsigned short* __restrict__ vtb,
        float* __restrict__ attnT) {
    __shared__ unsigned short ptA[4][32][36];   // per-wave P^T, stride 36 (72B)
    __shared__ unsigned short ptB[4][32][36];
    const int t = threadIdx.x, wave = t >> 6, lane = t & 63;
    const int r = lane & 15, g = lane >> 4;
    const int id = blockIdx.x;                   // 0..2047
    const int rest = id >> 3;                    // 0..255
    const int bh = (id & 7) * 4 + (rest >> 6);
    const int mid = rest & 63;
    const int qq = mid & 3, at = mid >> 2;       // qq 0..3, at 0..15
    const int b = bh >> 3, h = bh & 7;
    const int a0 = at * 128 + wave * 32;
    const int q00 = qq * 512;

    const unsigned short* kp = kb + ((size_t)bh * LL + a0 + r) * CH + 8 * g;
    const bf16x8 kf0 = *(const bf16x8*)kp;
    const bf16x8 kf1 = *(const bf16x8*)(kp + 16 * CH);
    const unsigned short* qp  = qb  + ((size_t)bh * LL + q00 + r) * CH + 8 * g;
    const unsigned short* vp0 = vtb + ((size_t)bh * CH + r) * LL + q00 + 8 * g;
    const unsigned short* vp1 = vp0 + (size_t)16 * LL;

    unsigned short* const bA = &ptA[wave][0][0];
    unsigned short* const bB = &ptB[wave][0][0];
    const int rd0 = r * 36 + 8 * g, rd1 = rd0 + 576;
    const int wr0 = r * 36 + 4 * g, wr1 = wr0 + 576;

    f32x4 acc00 = {0,0,0,0}, acc01 = {0,0,0,0}, acc10 = {0,0,0,0}, acc11 = {0,0,0,0};
    const f32x4 zero = {0.f, 0.f, 0.f, 0.f};

#define E2(x) __builtin_amdgcn_exp2f(x)
#define PACK2(s) make_uint2( \
        f2bf(E2((s)[0])) | (f2bf(E2((s)[1])) << 16), \
        f2bf(E2((s)[2])) | (f2bf(E2((s)[3])) << 16))

    // ---- prologue: compute & store P(0), prefetch q(1), load v(0) ----
    bf16x8 qn0 = *(const bf16x8*)qp;
    bf16x8 qn1 = *(const bf16x8*)(qp + 16 * CH);
    {
        f32x4 s00 = __builtin_amdgcn_mfma_f32_16x16x32_bf16(qn0, kf0, zero, 0, 0, 0);
        f32x4 s01 = __builtin_amdgcn_mfma_f32_16x16x32_bf16(qn0, kf1, zero, 0, 0, 0);
        f32x4 s10 = __builtin_amdgcn_mfma_f32_16x16x32_bf16(qn1, kf0, zero, 0, 0, 0);
        f32x4 s11 = __builtin_amdgcn_mfma_f32_16x16x32_bf16(qn1, kf1, zero, 0, 0, 0);
        *(uint2*)(bA + wr0)      = PACK2(s00);
        *(uint2*)(bA + wr1)      = PACK2(s01);
        *(uint2*)(bA + wr0 + 16) = PACK2(s10);
        *(uint2*)(bA + wr1 + 16) = PACK2(s11);
    }
    bf16x8 vc0 = *(const bf16x8*)vp0;
    bf16x8 vc1 = *(const bf16x8*)vp1;
    qn0 = *(const bf16x8*)(qp + 32 * CH);
    qn1 = *(const bf16x8*)(qp + 48 * CH);
    const unsigned short* qpn  = qp + 64 * CH;   // q frags for stage n+2
    const unsigned short* vpn0 = vp0 + 32;       // v frags for stage n+1
    const unsigned short* vpn1 = vp1 + 32;

#define STAGE(RD, WR, DOS, DOQ, DOV) do { \
    bf16x8 pa0 = *(const bf16x8*)((RD) + rd0); \
    bf16x8 pa1 = *(const bf16x8*)((RD) + rd1); \
    if (DOS) { \
        f32x4 s00 = __builtin_amdgcn_mfma_f32_16x16x32_bf16(qn0, kf0, zero, 0, 0, 0); \
        f32x4 s01 = __builtin_amdgcn_mfma_f32_16x16x32_bf16(qn0, kf1, zero, 0, 0, 0); \
        f32x4 s10 = __builtin_amdgcn_mfma_f32_16x16x32_bf16(qn1, kf0, zero, 0, 0, 0); \
        f32x4 s11 = __builtin_amdgcn_mfma_f32_16x16x32_bf16(qn1, kf1, zero, 0, 0, 0); \
        *(uint2*)((WR) + wr0)      = PACK2(s00); \
        *(uint2*)((WR) + wr1)      = PACK2(s01); \
        *(uint2*)((WR) + wr0 + 16) = PACK2(s10); \
        *(uint2*)((WR) + wr1 + 16) = PACK2(s11); \
    } \
    if (DOQ) { \
        qn0 = *(const bf16x8*)qpn; \
        qn1 = *(const bf16x8*)(qpn + 16 * CH); \
        qpn += 32 * CH; \
    } \
    __builtin_amdgcn_s_setprio(1); \
    acc00 = __builtin_amdgcn_mfma_f32_16x16x32_bf16(pa0, vc0, acc00, 0, 0, 0); \
    acc01 = __builtin_amdgcn_mfma_f32_16x16x32_bf16(pa0, vc1, acc01, 0, 0, 0); \
    acc10 = __builtin_amdgcn_mfma_f32_16x16x32_bf16(pa1, vc0, acc10, 0, 0, 0); \
    acc11 = __builtin_amdgcn_mfma_f32_16x16x32_bf16(pa1, vc1, acc11, 0, 0, 0); \
    __builtin_amdgcn_s_setprio(0); \
    if (DOV) { \
        vc0 = *(const bf16x8*)vpn0; \
        vc1 = *(const bf16x8*)vpn1; \
        vpn0 += 32; vpn1 += 32; \
    } \
} while (0)

    for (int nn = 0; nn < 7; ++nn) {
        STAGE(bA, bB, 1, 1, 1);    // stage 2nn
        STAGE(bB, bA, 1, 1, 1);    // stage 2nn+1
    }
    STAGE(bA, bB, 1, 0, 1);        // stage 14: compute/write P(15), load v(15)
    STAGE(bB, bA, 0, 0, 0);        // stage 15: PV only

#undef STAGE
#undef PACK2
#undef E2

    // f32 partial store: full 64B sector per row per instruction
    float* ob = attnT + ((size_t)qq * BB * HID + (size_t)b * HID + h * CH) * LL;
    *(f32x4*)(ob + (size_t)(r     ) * LL + a0 +      4 * g) = acc00;  // a-sub0, d=r
    *(f32x4*)(ob + (size_t)(16 + r) * LL + a0 +      4 * g) = acc01;  // a-sub0, d=16+r
    *(f32x4*)(ob + (size_t)(r     ) * LL + a0 + 16 + 4 * g) = acc10;  // a-sub1, d=r
    *(f32x4*)(ob + (size_t)(16 + r) * LL + a0 + 16 + 4 * g) = acc11;  // a-sub1, d=16+r
}

// ---------------------------------------------------------------------------
// Kernel 4: out[b,o,l] = BN( w_out @ (sum of 4 f32 partials) + b_out + x )
// ---------------------------------------------------------------------------
__global__ __launch_bounds__(256) void out_kernel(
        const float* __restrict__ attnT, const float* __restrict__ x,
        const float* __restrict__ w_out, const float* __restrict__ b_out,
        const float* __restrict__ bnw, const float* __restrict__ bnb,
        const float* __restrict__ bnm, const float* __restrict__ bnv,
        float* __restrict__ out) {
    __shared__ float wl[8 * 256];
    const int t = threadIdx.x;
    const int l0 = blockIdx.x * 256;
    const int o0 = blockIdx.y * 8;
    const int b  = blockIdx.z;

    const float4* ws = (const float4*)(w_out + (size_t)o0 * HID);
    float4* wd = (float4*)wl;
    #pragma unroll
    for (int r = 0; r < 2; ++r) wd[r * 256 + t] = ws[r * 256 + t];
    __syncthreads();

    float acc[8];
    #pragma unroll
    for (int j = 0; j < 8; ++j) acc[j] = 0.f;

    const size_t PART = (size_t)BB * HID * LL;   // floats per partial
    const float* ap = attnT + (size_t)b * HID * LL + l0 + t;
    for (int i = 0; i < HID; i += 4) {
        float a0, a1, a2, a3;
        {
            const float* p0 = ap + (size_t)(i+0) * LL;
            a0 = p0[0] + p0[PART] + p0[2*PART] + p0[3*PART];
            const float* p1 = ap + (size_t)(i+1) * LL;
            a1 = p1[0] + p1[PART] + p1[2*PART] + p1[3*PART];
            const float* p2 = ap + (size_t)(i+2) * LL;
            a2 = p2[0] + p2[PART] + p2[2*PART] + p2[3*PART];
            const float* p3 = ap + (size_t)(i+3) * LL;
            a3 = p3[0] + p3[PART] + p3[2*PART] + p3[3*PART];
        }
        #pragma unroll
        for (int j = 0; j < 8; ++j) {
            float4 w4 = *(const float4*)(wl + j * 256 + i);
            acc[j] += w4.x * a0 + w4.y * a1 + w4.z * a2 + w4.w * a3;
        }
    }
    #pragma unroll
    for (int j = 0; j < 8; ++j) {
        const int o = o0 + j;
        const float inv = bnw[o] / sqrtf(bnv[o] + 1e-5f);
        const float sh  = bnb[o] - bnm[o] * inv;
        const size_t idx = ((size_t)b * CIN + o) * LL + l0 + t;
        float val = acc[j] + b_out[o] + x[idx];
        out[idx] = val * inv + sh;
    }
}

// ---------------------------------------------------------------------------
extern "C" void kernel_launch(void* const* d_in, const int* in_sizes, int n_in,
                              void* d_out, int out_size, void* d_ws, size_t ws_size,
                              hipStream_t stream) {
    const float* x      = (const float*)d_in[0];
    const float* w_qkv  = (const float*)d_in[1];
    const float* b_qkv  = (const float*)d_in[2];
    const float* w_out  = (const float*)d_in[3];
    const float* b_out  = (const float*)d_in[4];
    const float* bnw    = (const float*)d_in[5];
    const float* bnb    = (const float*)d_in[6];
    const float* bnm    = (const float*)d_in[7];
    const float* bnv    = (const float*)d_in[8];
    float* out = (float*)d_out;

    const size_t NBH = (size_t)BB * HH;          // 32
    const size_t QKV_ELEMS = NBH * LL * CH;      // 2,097,152 bf16 elems each
    unsigned short* qb    = (unsigned short*)d_ws;
    unsigned short* kb    = qb + QKV_ELEMS;
    unsigned short* vtb   = kb + QKV_ELEMS;
    float* attnT = (float*)(vtb + QKV_ELEMS);    // 4 x 8 MB f32 partials

    qkv_kernel<<<dim3(32, 24, BB), 256, 0, stream>>>(x, w_qkv, b_qkv, qb, kb, vtb);
    denom_mfma<<<dim3(1024), 512, 0, stream>>>(qb, kb, vtb);
    attn_mfma<<<dim3(2048), 256, 0, stream>>>(qb, kb, vtb, attnT);
    out_kernel<<<dim3(8, 16, BB), 256, 0, stream>>>(attnT, x, w_out, b_out,
                                                    bnw, bnb, bnm, bnv, out);
}

// Round 7
// 149.753 us; speedup vs baseline: 1.3181x; 1.2115x over previous
//
#include <hip/hip_runtime.h>
#include <math.h>

#define BB 4
#define CIN 128
#define LL 2048
#define HH 8
#define CH 32
#define HID 256

typedef __attribute__((ext_vector_type(8))) __bf16 bf16x8;
typedef __attribute__((ext_vector_type(4))) float f32x4;

static __device__ __forceinline__ unsigned int f2bf(float f) {
    union { __bf16 b; unsigned short s; } u;
    u.b = (__bf16)f;
    return (unsigned int)u.s;
}
static __device__ __forceinline__ float bf2f(unsigned int s) {
    union { float f; unsigned int u; } x;
    x.u = s << 16;
    return x.f;
}

// ---------------------------------------------------------------------------
// Kernel 1: QKV 1x1 conv -> bf16 buffers.
// Q: [bh][l][d] bf16, pre-scaled by log2(e)/sqrt(L) (so exp(s) == exp2(s')).
// K: [bh][l][d] bf16.  V: transposed [bh][d][l] bf16.
// ---------------------------------------------------------------------------
__global__ __launch_bounds__(256) void qkv_kernel(
        const float* __restrict__ x, const float* __restrict__ w_qkv,
        const float* __restrict__ b_qkv,
        unsigned short* __restrict__ qb, unsigned short* __restrict__ kb,
        unsigned short* __restrict__ vtb) {
    __shared__ float wl[32 * 128];
    __shared__ float tr[32 * 65];
    const int t = threadIdx.x;
    const int lt = blockIdx.x;           // 0..31
    const int g  = blockIdx.y;           // 0..23 : sel*8 + h
    const int b  = blockIdx.z;
    const int sel = g >> 3, h = g & 7;
    const int obase = sel * 256 + h * 32;
    const int l0 = lt * 64;

    const float4* wsrc = (const float4*)(w_qkv + (size_t)obase * CIN);
    float4* wdst = (float4*)wl;
    #pragma unroll
    for (int r = 0; r < 4; ++r) wdst[r * 256 + t] = wsrc[r * 256 + t];
    __syncthreads();

    const int ll = t & 63, og = t >> 6;
    float acc[8] = {0.f,0.f,0.f,0.f,0.f,0.f,0.f,0.f};
    const float* xp = x + (size_t)b * CIN * LL + l0 + ll;
    for (int i = 0; i < CIN; i += 4) {
        float x0 = xp[(size_t)(i+0) * LL];
        float x1 = xp[(size_t)(i+1) * LL];
        float x2 = xp[(size_t)(i+2) * LL];
        float x3 = xp[(size_t)(i+3) * LL];
        #pragma unroll
        for (int j = 0; j < 8; ++j) {
            float4 w4 = *(const float4*)(wl + (og * 8 + j) * 128 + i);
            acc[j] += w4.x * x0 + w4.y * x1 + w4.z * x2 + w4.w * x3;
        }
    }
    // log2(e)/sqrt(2048)
    const float scale = (sel == 0) ? 0.03187935835f : 1.0f;
    #pragma unroll
    for (int j = 0; j < 8; ++j) {
        int oc = og * 8 + j;
        tr[oc * 65 + ll] = (acc[j] + b_qkv[obase + oc]) * scale;   // [c][l]
    }
    __syncthreads();
    if (sel == 2) {
        unsigned short* dst = vtb + ((size_t)(b * HH + h) * CH) * LL + l0;
        #pragma unroll
        for (int r = 0; r < 8; ++r) {
            int flat = r * 256 + t;           // c*64 + l
            int c = flat >> 6, l = flat & 63;
            dst[(size_t)c * LL + l] = (unsigned short)f2bf(tr[c * 65 + l]);
        }
    } else {
        unsigned short* dst = (sel == 0 ? qb : kb)
                              + ((size_t)(b * HH + h) * LL + l0) * CH;
        #pragma unroll
        for (int r = 0; r < 8; ++r) {
            int flat = r * 256 + t;           // lr*32 + c
            int c = flat & 31, lr = flat >> 5;
            dst[flat] = (unsigned short)f2bf(tr[c * 65 + lr]);
        }
    }
}

// ---------------------------------------------------------------------------
// Kernel 2: softmax denominators via MFMA, then scale V^T in place.
// 512 threads: waves 0-3 sum a in [0,1024), waves 4-7 in [1024,2048);
// LDS-combine, then vtb[bh][d][q] *= 1/z[q].
// ---------------------------------------------------------------------------
__global__ __launch_bounds__(512) void denom_mfma(
        const unsigned short* __restrict__ qb,
        const unsigned short* __restrict__ kb,
        unsigned short* __restrict__ vtb) {
    __shared__ float zz[2][64];
    const int t = threadIdx.x, wave = t >> 6, lane = t & 63;
    const int id = blockIdx.x;
    const int bh = (id & 7) * 4 + ((id >> 3) >> 5);
    const int qt = (id >> 3) & 31;
    const int ah = wave >> 2, wsub = wave & 3;
    const int q0 = qt * 64 + wsub * 16;
    const int r = lane & 15, g = lane >> 4;

    bf16x8 afrag = *(const bf16x8*)(qb + ((size_t)bh * LL + q0 + r) * CH + 8 * g);
    const unsigned short* kp = kb + ((size_t)bh * LL + r) * CH + 8 * g;

    float z0 = 0.f, z1 = 0.f, z2 = 0.f, z3 = 0.f;
    const f32x4 zero = {0.f, 0.f, 0.f, 0.f};
    for (int a0 = ah * 1024; a0 < ah * 1024 + 1024; a0 += 64) {
        #pragma unroll
        for (int s = 0; s < 4; ++s) {
            bf16x8 bfrag = *(const bf16x8*)(kp + (size_t)(a0 + s * 16) * CH);
            f32x4 d = __builtin_amdgcn_mfma_f32_16x16x32_bf16(afrag, bfrag, zero, 0, 0, 0);
            z0 += __builtin_amdgcn_exp2f(d[0]);
            z1 += __builtin_amdgcn_exp2f(d[1]);
            z2 += __builtin_amdgcn_exp2f(d[2]);
            z3 += __builtin_amdgcn_exp2f(d[3]);
        }
    }
    #pragma unroll
    for (int m = 1; m < 16; m <<= 1) {
        z0 += __shfl_xor(z0, m); z1 += __shfl_xor(z1, m);
        z2 += __shfl_xor(z2, m); z3 += __shfl_xor(z3, m);
    }
    if (r == 0) {
        *(float4*)&zz[ah][wsub * 16 + 4 * g] = make_float4(z0, z1, z2, z3);
    }
    __syncthreads();

    // scale vtb[bh][d][qt*64 .. +63]: 512 thr x 4 elems = 32 d x 64 q
    const int d = t >> 4, qo = (t & 15) * 4;
    const float i0 = 1.f / (zz[0][qo + 0] + zz[1][qo + 0]);
    const float i1 = 1.f / (zz[0][qo + 1] + zz[1][qo + 1]);
    const float i2 = 1.f / (zz[0][qo + 2] + zz[1][qo + 2]);
    const float i3 = 1.f / (zz[0][qo + 3] + zz[1][qo + 3]);
    unsigned short* vrow = vtb + ((size_t)bh * CH + d) * LL + qt * 64 + qo;
    uint2 v = *(const uint2*)vrow;
    unsigned int w0, w1;
    w0 = f2bf(bf2f(v.x & 0xFFFFu) * i0) | (f2bf(bf2f(v.x >> 16) * i1) << 16);
    w1 = f2bf(bf2f(v.y & 0xFFFFu) * i2) | (f2bf(bf2f(v.y >> 16) * i3) << 16);
    *(uint2*)vrow = make_uint2(w0, w1);
}

// ---------------------------------------------------------------------------
// Kernel 3: attn^T via MFMA, software-pipelined per-wave LDS P^T bounce.
// q split into 2 halves (qh); partial sums stored as f32x4 (clean sectors).
// attnT[qh][b][h*32+d][a] = sum_{q in half} exp2(s') V'[q,d]
// launch_bounds(256,4): 128-VGPR cap -> no scratch spills (R5/R6 lesson).
// ---------------------------------------------------------------------------
__global__ __launch_bounds__(256, 4) void attn_mfma(
        const unsigned short* __restrict__ qb,
        const unsigned short* __restrict__ kb,
        const unsigned short* __restrict__ vtb,
        float* __restrict__ attnT) {
    __shared__ unsigned short ptA[4][32][36];   // per-wave P^T, stride 36 (72B)
    __shared__ unsigned short ptB[4][32][36];
    const int t = threadIdx.x, wave = t >> 6, lane = t & 63;
    const int r = lane & 15, g = lane >> 4;
    const int id = blockIdx.x;                   // 0..1023
    const int rest = id >> 3;                    // 0..127
    const int bh = (id & 7) * 4 + (rest >> 5);
    const int mid = rest & 31;
    const int qh = mid & 1, at = mid >> 1;       // qh 0..1, at 0..15
    const int b = bh >> 3, h = bh & 7;
    const int a0 = at * 128 + wave * 32;
    const int q00 = qh * 1024;

    const unsigned short* kp = kb + ((size_t)bh * LL + a0 + r) * CH + 8 * g;
    const bf16x8 kf0 = *(const bf16x8*)kp;
    const bf16x8 kf1 = *(const bf16x8*)(kp + 16 * CH);
    const unsigned short* qp  = qb  + ((size_t)bh * LL + q00 + r) * CH + 8 * g;
    const unsigned short* vp0 = vtb + ((size_t)bh * CH + r) * LL + q00 + 8 * g;
    const unsigned short* vp1 = vp0 + (size_t)16 * LL;

    unsigned short* const bA = &ptA[wave][0][0];
    unsigned short* const bB = &ptB[wave][0][0];
    const int rd0 = r * 36 + 8 * g, rd1 = rd0 + 576;
    const int wr0 = r * 36 + 4 * g, wr1 = wr0 + 576;

    f32x4 acc00 = {0,0,0,0}, acc01 = {0,0,0,0}, acc10 = {0,0,0,0}, acc11 = {0,0,0,0};
    const f32x4 zero = {0.f, 0.f, 0.f, 0.f};

#define E2(x) __builtin_amdgcn_exp2f(x)
#define PACK2(s) make_uint2( \
        f2bf(E2((s)[0])) | (f2bf(E2((s)[1])) << 16), \
        f2bf(E2((s)[2])) | (f2bf(E2((s)[3])) << 16))

    // ---- prologue: compute & store P(0), prefetch q(1), load v(0) ----
    bf16x8 qn0 = *(const bf16x8*)qp;
    bf16x8 qn1 = *(const bf16x8*)(qp + 16 * CH);
    {
        f32x4 s00 = __builtin_amdgcn_mfma_f32_16x16x32_bf16(qn0, kf0, zero, 0, 0, 0);
        f32x4 s01 = __builtin_amdgcn_mfma_f32_16x16x32_bf16(qn0, kf1, zero, 0, 0, 0);
        f32x4 s10 = __builtin_amdgcn_mfma_f32_16x16x32_bf16(qn1, kf0, zero, 0, 0, 0);
        f32x4 s11 = __builtin_amdgcn_mfma_f32_16x16x32_bf16(qn1, kf1, zero, 0, 0, 0);
        *(uint2*)(bA + wr0)      = PACK2(s00);
        *(uint2*)(bA + wr1)      = PACK2(s01);
        *(uint2*)(bA + wr0 + 16) = PACK2(s10);
        *(uint2*)(bA + wr1 + 16) = PACK2(s11);
    }
    bf16x8 vc0 = *(const bf16x8*)vp0;
    bf16x8 vc1 = *(const bf16x8*)vp1;
    qn0 = *(const bf16x8*)(qp + 32 * CH);
    qn1 = *(const bf16x8*)(qp + 48 * CH);
    const unsigned short* qpn  = qp + 64 * CH;   // q frags for stage n+2
    const unsigned short* vpn0 = vp0 + 32;       // v frags for stage n+1
    const unsigned short* vpn1 = vp1 + 32;

#define STAGE(RD, WR, DOS, DOQ, DOV) do { \
    bf16x8 pa0 = *(const bf16x8*)((RD) + rd0); \
    bf16x8 pa1 = *(const bf16x8*)((RD) + rd1); \
    if (DOS) { \
        f32x4 s00 = __builtin_amdgcn_mfma_f32_16x16x32_bf16(qn0, kf0, zero, 0, 0, 0); \
        f32x4 s01 = __builtin_amdgcn_mfma_f32_16x16x32_bf16(qn0, kf1, zero, 0, 0, 0); \
        f32x4 s10 = __builtin_amdgcn_mfma_f32_16x16x32_bf16(qn1, kf0, zero, 0, 0, 0); \
        f32x4 s11 = __builtin_amdgcn_mfma_f32_16x16x32_bf16(qn1, kf1, zero, 0, 0, 0); \
        *(uint2*)((WR) + wr0)      = PACK2(s00); \
        *(uint2*)((WR) + wr1)      = PACK2(s01); \
        *(uint2*)((WR) + wr0 + 16) = PACK2(s10); \
        *(uint2*)((WR) + wr1 + 16) = PACK2(s11); \
    } \
    if (DOQ) { \
        qn0 = *(const bf16x8*)qpn; \
        qn1 = *(const bf16x8*)(qpn + 16 * CH); \
        qpn += 32 * CH; \
    } \
    __builtin_amdgcn_s_setprio(1); \
    acc00 = __builtin_amdgcn_mfma_f32_16x16x32_bf16(pa0, vc0, acc00, 0, 0, 0); \
    acc01 = __builtin_amdgcn_mfma_f32_16x16x32_bf16(pa0, vc1, acc01, 0, 0, 0); \
    acc10 = __builtin_amdgcn_mfma_f32_16x16x32_bf16(pa1, vc0, acc10, 0, 0, 0); \
    acc11 = __builtin_amdgcn_mfma_f32_16x16x32_bf16(pa1, vc1, acc11, 0, 0, 0); \
    __builtin_amdgcn_s_setprio(0); \
    if (DOV) { \
        vc0 = *(const bf16x8*)vpn0; \
        vc1 = *(const bf16x8*)vpn1; \
        vpn0 += 32; vpn1 += 32; \
    } \
} while (0)

    for (int nn = 0; nn < 15; ++nn) {
        STAGE(bA, bB, 1, 1, 1);    // stage 2nn
        STAGE(bB, bA, 1, 1, 1);    // stage 2nn+1
    }
    STAGE(bA, bB, 1, 0, 1);        // stage 30: compute/write P(31), load v(31)
    STAGE(bB, bA, 0, 0, 0);        // stage 31: PV only

#undef STAGE
#undef PACK2
#undef E2

    // f32 partial store: full 64B sector per row per instruction
    float* ob = attnT + ((size_t)qh * BB * HID + (size_t)b * HID + h * CH) * LL;
    *(f32x4*)(ob + (size_t)(r     ) * LL + a0 +      4 * g) = acc00;  // a-sub0, d=r
    *(f32x4*)(ob + (size_t)(16 + r) * LL + a0 +      4 * g) = acc01;  // a-sub0, d=16+r
    *(f32x4*)(ob + (size_t)(r     ) * LL + a0 + 16 + 4 * g) = acc10;  // a-sub1, d=r
    *(f32x4*)(ob + (size_t)(16 + r) * LL + a0 + 16 + 4 * g) = acc11;  // a-sub1, d=16+r
}

// ---------------------------------------------------------------------------
// Kernel 4: out[b,o,l] = BN( w_out @ (sum of 2 f32 partials) + b_out + x )
// ---------------------------------------------------------------------------
__global__ __launch_bounds__(256) void out_kernel(
        const float* __restrict__ attnT, const float* __restrict__ x,
        const float* __restrict__ w_out, const float* __restrict__ b_out,
        const float* __restrict__ bnw, const float* __restrict__ bnb,
        const float* __restrict__ bnm, const float* __restrict__ bnv,
        float* __restrict__ out) {
    __shared__ float wl[8 * 256];
    const int t = threadIdx.x;
    const int l0 = blockIdx.x * 256;
    const int o0 = blockIdx.y * 8;
    const int b  = blockIdx.z;

    const float4* ws = (const float4*)(w_out + (size_t)o0 * HID);
    float4* wd = (float4*)wl;
    #pragma unroll
    for (int r = 0; r < 2; ++r) wd[r * 256 + t] = ws[r * 256 + t];
    __syncthreads();

    float acc[8];
    #pragma unroll
    for (int j = 0; j < 8; ++j) acc[j] = 0.f;

    const size_t PART = (size_t)BB * HID * LL;   // floats per partial
    const float* ap = attnT + (size_t)b * HID * LL + l0 + t;
    for (int i = 0; i < HID; i += 4) {
        const float* p0 = ap + (size_t)(i+0) * LL;
        const float* p1 = ap + (size_t)(i+1) * LL;
        const float* p2 = ap + (size_t)(i+2) * LL;
        const float* p3 = ap + (size_t)(i+3) * LL;
        float a0 = p0[0] + p0[PART];
        float a1 = p1[0] + p1[PART];
        float a2 = p2[0] + p2[PART];
        float a3 = p3[0] + p3[PART];
        #pragma unroll
        for (int j = 0; j < 8; ++j) {
            float4 w4 = *(const float4*)(wl + j * 256 + i);
            acc[j] += w4.x * a0 + w4.y * a1 + w4.z * a2 + w4.w * a3;
        }
    }
    #pragma unroll
    for (int j = 0; j < 8; ++j) {
        const int o = o0 + j;
        const float inv = bnw[o] / sqrtf(bnv[o] + 1e-5f);
        const float sh  = bnb[o] - bnm[o] * inv;
        const size_t idx = ((size_t)b * CIN + o) * LL + l0 + t;
        float val = acc[j] + b_out[o] + x[idx];
        out[idx] = val * inv + sh;
    }
}

// ---------------------------------------------------------------------------
extern "C" void kernel_launch(void* const* d_in, const int* in_sizes, int n_in,
                              void* d_out, int out_size, void* d_ws, size_t ws_size,
                              hipStream_t stream) {
    const float* x      = (const float*)d_in[0];
    const float* w_qkv  = (const float*)d_in[1];
    const float* b_qkv  = (const float*)d_in[2];
    const float* w_out  = (const float*)d_in[3];
    const float* b_out  = (const float*)d_in[4];
    const float* bnw    = (const float*)d_in[5];
    const float* bnb    = (const float*)d_in[6];
    const float* bnm    = (const float*)d_in[7];
    const float* bnv    = (const float*)d_in[8];
    float* out = (float*)d_out;

    const size_t NBH = (size_t)BB * HH;          // 32
    const size_t QKV_ELEMS = NBH * LL * CH;      // 2,097,152 bf16 elems each
    unsigned short* qb    = (unsigned short*)d_ws;
    unsigned short* kb    = qb + QKV_ELEMS;
    unsigned short* vtb   = kb + QKV_ELEMS;
    float* attnT = (float*)(vtb + QKV_ELEMS);    // 2 x 8 MB f32 partials

    qkv_kernel<<<dim3(32, 24, BB), 256, 0, stream>>>(x, w_qkv, b_qkv, qb, kb, vtb);
    denom_mfma<<<dim3(1024), 512, 0, stream>>>(qb, kb, vtb);
    attn_mfma<<<dim3(1024), 256, 0, stream>>>(qb, kb, vtb, attnT);
    out_kernel<<<dim3(8, 16, BB), 256, 0, stream>>>(attnT, x, w_out, b_out,
                                                    bnw, bnb, bnm, bnv, out);
}

// Round 8
// 148.296 us; speedup vs baseline: 1.3311x; 1.0098x over previous
//
#include <hip/hip_runtime.h>
#include <math.h>

#define BB 4
#define CIN 128
#define LL 2048
#define HH 8
#define CH 32
#define HID 256

typedef __attribute__((ext_vector_type(8))) __bf16 bf16x8;
typedef __attribute__((ext_vector_type(4))) float f32x4;

static __device__ __forceinline__ unsigned int f2bf(float f) {
    union { __bf16 b; unsigned short s; } u;
    u.b = (__bf16)f;
    return (unsigned int)u.s;
}
static __device__ __forceinline__ float bf2f(unsigned int s) {
    union { float f; unsigned int u; } x;
    x.u = s << 16;
    return x.f;
}

#define MFMA __builtin_amdgcn_mfma_f32_16x16x32_bf16

// ---------------------------------------------------------------------------
// Kernel 1: QKV 1x1 conv -> bf16 buffers.
// Q: [bh][l][d] bf16, pre-scaled by log2(e)/sqrt(L) (so exp(s) == exp2(s')).
// K: [bh][l][d] bf16.  V: transposed [bh][d][l] bf16.
// ---------------------------------------------------------------------------
__global__ __launch_bounds__(256) void qkv_kernel(
        const float* __restrict__ x, const float* __restrict__ w_qkv,
        const float* __restrict__ b_qkv,
        unsigned short* __restrict__ qb, unsigned short* __restrict__ kb,
        unsigned short* __restrict__ vtb) {
    __shared__ float wl[32 * 128];
    __shared__ float tr[32 * 65];
    const int t = threadIdx.x;
    const int lt = blockIdx.x;           // 0..31
    const int g  = blockIdx.y;           // 0..23 : sel*8 + h
    const int b  = blockIdx.z;
    const int sel = g >> 3, h = g & 7;
    const int obase = sel * 256 + h * 32;
    const int l0 = lt * 64;

    const float4* wsrc = (const float4*)(w_qkv + (size_t)obase * CIN);
    float4* wdst = (float4*)wl;
    #pragma unroll
    for (int r = 0; r < 4; ++r) wdst[r * 256 + t] = wsrc[r * 256 + t];
    __syncthreads();

    const int ll = t & 63, og = t >> 6;
    float acc[8] = {0.f,0.f,0.f,0.f,0.f,0.f,0.f,0.f};
    const float* xp = x + (size_t)b * CIN * LL + l0 + ll;
    for (int i = 0; i < CIN; i += 4) {
        float x0 = xp[(size_t)(i+0) * LL];
        float x1 = xp[(size_t)(i+1) * LL];
        float x2 = xp[(size_t)(i+2) * LL];
        float x3 = xp[(size_t)(i+3) * LL];
        #pragma unroll
        for (int j = 0; j < 8; ++j) {
            float4 w4 = *(const float4*)(wl + (og * 8 + j) * 128 + i);
            acc[j] += w4.x * x0 + w4.y * x1 + w4.z * x2 + w4.w * x3;
        }
    }
    // log2(e)/sqrt(2048)
    const float scale = (sel == 0) ? 0.03187935835f : 1.0f;
    #pragma unroll
    for (int j = 0; j < 8; ++j) {
        int oc = og * 8 + j;
        tr[oc * 65 + ll] = (acc[j] + b_qkv[obase + oc]) * scale;   // [c][l]
    }
    __syncthreads();
    if (sel == 2) {
        unsigned short* dst = vtb + ((size_t)(b * HH + h) * CH) * LL + l0;
        #pragma unroll
        for (int r = 0; r < 8; ++r) {
            int flat = r * 256 + t;           // c*64 + l
            int c = flat >> 6, l = flat & 63;
            dst[(size_t)c * LL + l] = (unsigned short)f2bf(tr[c * 65 + l]);
        }
    } else {
        unsigned short* dst = (sel == 0 ? qb : kb)
                              + ((size_t)(b * HH + h) * LL + l0) * CH;
        #pragma unroll
        for (int r = 0; r < 8; ++r) {
            int flat = r * 256 + t;           // lr*32 + c
            int c = flat & 31, lr = flat >> 5;
            dst[flat] = (unsigned short)f2bf(tr[c * 65 + lr]);
        }
    }
}

// ---------------------------------------------------------------------------
// Kernel 2: softmax denominators via MFMA (K-frag prefetch pipelined), then
// scale V^T in place.  512 threads: waves 0-3 sum a in [0,1024), 4-7 the rest.
// ---------------------------------------------------------------------------
__global__ __launch_bounds__(512) void denom_mfma(
        const unsigned short* __restrict__ qb,
        const unsigned short* __restrict__ kb,
        unsigned short* __restrict__ vtb) {
    __shared__ float zz[2][64];
    const int t = threadIdx.x, wave = t >> 6, lane = t & 63;
    const int id = blockIdx.x;
    const int bh = (id & 7) * 4 + ((id >> 3) >> 5);
    const int qt = (id >> 3) & 31;
    const int ah = wave >> 2, wsub = wave & 3;
    const int q0 = qt * 64 + wsub * 16;
    const int r = lane & 15, g = lane >> 4;

    bf16x8 afrag = *(const bf16x8*)(qb + ((size_t)bh * LL + q0 + r) * CH + 8 * g);
    const unsigned short* kp = kb + ((size_t)bh * LL + ah * 1024 + r) * CH + 8 * g;

    float z0 = 0.f, z1 = 0.f, z2 = 0.f, z3 = 0.f;
    const f32x4 zero = {0.f, 0.f, 0.f, 0.f};
    // prefetch-pipelined: 16 iterations of 64 a
    bf16x8 n0 = *(const bf16x8*)(kp);
    bf16x8 n1 = *(const bf16x8*)(kp + 16 * CH);
    bf16x8 n2 = *(const bf16x8*)(kp + 32 * CH);
    bf16x8 n3 = *(const bf16x8*)(kp + 48 * CH);
    for (int it = 0; it < 16; ++it) {
        bf16x8 c0 = n0, c1 = n1, c2 = n2, c3 = n3;
        if (it < 15) {
            const unsigned short* np = kp + (size_t)(it + 1) * 64 * CH;
            n0 = *(const bf16x8*)(np);
            n1 = *(const bf16x8*)(np + 16 * CH);
            n2 = *(const bf16x8*)(np + 32 * CH);
            n3 = *(const bf16x8*)(np + 48 * CH);
        }
        f32x4 d0 = MFMA(afrag, c0, zero, 0, 0, 0);
        f32x4 d1 = MFMA(afrag, c1, zero, 0, 0, 0);
        f32x4 d2 = MFMA(afrag, c2, zero, 0, 0, 0);
        f32x4 d3 = MFMA(afrag, c3, zero, 0, 0, 0);
        z0 += __builtin_amdgcn_exp2f(d0[0]) + __builtin_amdgcn_exp2f(d1[0])
            + __builtin_amdgcn_exp2f(d2[0]) + __builtin_amdgcn_exp2f(d3[0]);
        z1 += __builtin_amdgcn_exp2f(d0[1]) + __builtin_amdgcn_exp2f(d1[1])
            + __builtin_amdgcn_exp2f(d2[1]) + __builtin_amdgcn_exp2f(d3[1]);
        z2 += __builtin_amdgcn_exp2f(d0[2]) + __builtin_amdgcn_exp2f(d1[2])
            + __builtin_amdgcn_exp2f(d2[2]) + __builtin_amdgcn_exp2f(d3[2]);
        z3 += __builtin_amdgcn_exp2f(d0[3]) + __builtin_amdgcn_exp2f(d1[3])
            + __builtin_amdgcn_exp2f(d2[3]) + __builtin_amdgcn_exp2f(d3[3]);
    }
    #pragma unroll
    for (int m = 1; m < 16; m <<= 1) {
        z0 += __shfl_xor(z0, m); z1 += __shfl_xor(z1, m);
        z2 += __shfl_xor(z2, m); z3 += __shfl_xor(z3, m);
    }
    if (r == 0) {
        *(float4*)&zz[ah][wsub * 16 + 4 * g] = make_float4(z0, z1, z2, z3);
    }
    __syncthreads();

    // scale vtb[bh][d][qt*64 .. +63]: 512 thr x 4 elems = 32 d x 64 q
    const int d = t >> 4, qo = (t & 15) * 4;
    const float i0 = 1.f / (zz[0][qo + 0] + zz[1][qo + 0]);
    const float i1 = 1.f / (zz[0][qo + 1] + zz[1][qo + 1]);
    const float i2 = 1.f / (zz[0][qo + 2] + zz[1][qo + 2]);
    const float i3 = 1.f / (zz[0][qo + 3] + zz[1][qo + 3]);
    unsigned short* vrow = vtb + ((size_t)bh * CH + d) * LL + qt * 64 + qo;
    uint2 v = *(const uint2*)vrow;
    unsigned int w0, w1;
    w0 = f2bf(bf2f(v.x & 0xFFFFu) * i0) | (f2bf(bf2f(v.x >> 16) * i1) << 16);
    w1 = f2bf(bf2f(v.y & 0xFFFFu) * i2) | (f2bf(bf2f(v.y >> 16) * i3) << 16);
    *(uint2*)vrow = make_uint2(w0, w1);
}

// ---------------------------------------------------------------------------
// Kernel 3: attn^T via MFMA, software-pipelined, 64-q stages (16 stages).
// Per wave: 32 a-cols x 32 d.  Stage n: read P(n), compute+write P(n+1),
// PV(n), prefetch q(n+2), v(n+1).  LDS: two R7-proven stride-36 tiles
// (one per 32-q k-block) per wave, double-buffered.
// ---------------------------------------------------------------------------
__global__ __launch_bounds__(256, 4) void attn_mfma(
        const unsigned short* __restrict__ qb,
        const unsigned short* __restrict__ kb,
        const unsigned short* __restrict__ vtb,
        float* __restrict__ attnT) {
    __shared__ unsigned short ptA[4][2][32][36];   // [wave][ks][a][q-in-block]
    __shared__ unsigned short ptB[4][2][32][36];
    const int t = threadIdx.x, wave = t >> 6, lane = t & 63;
    const int r = lane & 15, g = lane >> 4;
    const int id = blockIdx.x;                   // 0..1023
    const int rest = id >> 3;                    // 0..127
    const int bh = (id & 7) * 4 + (rest >> 5);
    const int mid = rest & 31;
    const int qh = mid & 1, at = mid >> 1;       // qh 0..1, at 0..15
    const int b = bh >> 3, h = bh & 7;
    const int a0 = at * 128 + wave * 32;
    const int q00 = qh * 1024;

    const unsigned short* kp = kb + ((size_t)bh * LL + a0 + r) * CH + 8 * g;
    const bf16x8 kf0 = *(const bf16x8*)kp;
    const bf16x8 kf1 = *(const bf16x8*)(kp + 16 * CH);
    const unsigned short* qp = qb  + ((size_t)bh * LL + q00 + r) * CH + 8 * g;
    const unsigned short* vp = vtb + ((size_t)bh * CH + r) * LL + q00 + 8 * g;

    unsigned short* const bA = &ptA[wave][0][0][0];
    unsigned short* const bB = &ptB[wave][0][0][0];
    // write (as, qs): qs>>1 selects ks tile (stride 1152), qs&1 selects 16-col half
    const int wb = r * 36 + 4 * g;               // + as*576 + (qs&1)*16 + (qs>>1)*1152
    const int rb = r * 36 + 8 * g;               // + as*576 + ks*1152

    f32x4 acc00 = {0,0,0,0}, acc01 = {0,0,0,0}, acc10 = {0,0,0,0}, acc11 = {0,0,0,0};
    const f32x4 zero = {0.f, 0.f, 0.f, 0.f};

#define E2(x) __builtin_amdgcn_exp2f(x)
#define PACK2(s) make_uint2( \
        f2bf(E2((s)[0])) | (f2bf(E2((s)[1])) << 16), \
        f2bf(E2((s)[2])) | (f2bf(E2((s)[3])) << 16))

#define SCLUSTER(WR) do { \
    f32x4 s_; \
    s_ = MFMA(qn0, kf0, zero, 0, 0, 0); *(uint2*)((WR) + wb)               = PACK2(s_); \
    s_ = MFMA(qn0, kf1, zero, 0, 0, 0); *(uint2*)((WR) + wb + 576)         = PACK2(s_); \
    s_ = MFMA(qn1, kf0, zero, 0, 0, 0); *(uint2*)((WR) + wb + 16)          = PACK2(s_); \
    s_ = MFMA(qn1, kf1, zero, 0, 0, 0); *(uint2*)((WR) + wb + 576 + 16)    = PACK2(s_); \
    s_ = MFMA(qn2, kf0, zero, 0, 0, 0); *(uint2*)((WR) + wb + 1152)        = PACK2(s_); \
    s_ = MFMA(qn2, kf1, zero, 0, 0, 0); *(uint2*)((WR) + wb + 1152 + 576)  = PACK2(s_); \
    s_ = MFMA(qn3, kf0, zero, 0, 0, 0); *(uint2*)((WR) + wb + 1152 + 16)   = PACK2(s_); \
    s_ = MFMA(qn3, kf1, zero, 0, 0, 0); *(uint2*)((WR) + wb + 1152 + 592)  = PACK2(s_); \
} while (0)

#define LOADQ(n) do { \
    qn0 = *(const bf16x8*)(qpn); \
    qn1 = *(const bf16x8*)(qpn + 16 * CH); \
    qn2 = *(const bf16x8*)(qpn + 32 * CH); \
    qn3 = *(const bf16x8*)(qpn + 48 * CH); \
    qpn += 64 * CH; \
} while (0)

    // ---- prologue ----
    bf16x8 qn0, qn1, qn2, qn3;
    const unsigned short* qpn = qp;
    LOADQ(0);                      // Q(0)
    SCLUSTER(bA);                  // P(0) -> bufA
    bf16x8 vc00 = *(const bf16x8*)(vp);
    bf16x8 vc01 = *(const bf16x8*)(vp + 32);
    bf16x8 vc10 = *(const bf16x8*)(vp + 16 * LL);
    bf16x8 vc11 = *(const bf16x8*)(vp + 16 * LL + 32);
    LOADQ(1);                      // Q(1) for stage 0's S-cluster
    const unsigned short* vpn = vp + 64;

#define STAGE(RD, WR, DOS, DOQ, DOV) do { \
    bf16x8 pa00 = *(const bf16x8*)((RD) + rb);               /* as0 ks0 */ \
    bf16x8 pa01 = *(const bf16x8*)((RD) + rb + 1152);        /* as0 ks1 */ \
    bf16x8 pa10 = *(const bf16x8*)((RD) + rb + 576);         /* as1 ks0 */ \
    bf16x8 pa11 = *(const bf16x8*)((RD) + rb + 1152 + 576);  /* as1 ks1 */ \
    if (DOS) SCLUSTER(WR); \
    if (DOQ) LOADQ(0); \
    __builtin_amdgcn_s_setprio(1); \
    acc00 = MFMA(pa00, vc00, acc00, 0, 0, 0); \
    acc00 = MFMA(pa01, vc01, acc00, 0, 0, 0); \
    acc01 = MFMA(pa00, vc10, acc01, 0, 0, 0); \
    acc01 = MFMA(pa01, vc11, acc01, 0, 0, 0); \
    acc10 = MFMA(pa10, vc00, acc10, 0, 0, 0); \
    acc10 = MFMA(pa11, vc01, acc10, 0, 0, 0); \
    acc11 = MFMA(pa10, vc10, acc11, 0, 0, 0); \
    acc11 = MFMA(pa11, vc11, acc11, 0, 0, 0); \
    __builtin_amdgcn_s_setprio(0); \
    if (DOV) { \
        vc00 = *(const bf16x8*)(vpn); \
        vc01 = *(const bf16x8*)(vpn + 32); \
        vc10 = *(const bf16x8*)(vpn + 16 * LL); \
        vc11 = *(const bf16x8*)(vpn + 16 * LL + 32); \
        vpn += 64; \
    } \
} while (0)

    for (int nn = 0; nn < 7; ++nn) {
        STAGE(bA, bB, 1, 1, 1);    // even stage
        STAGE(bB, bA, 1, 1, 1);    // odd stage
    }
    STAGE(bA, bB, 1, 0, 1);        // stage 14: compute/write P(15), load v(15)
    STAGE(bB, bA, 0, 0, 0);        // stage 15: PV only

#undef STAGE
#undef LOADQ
#undef SCLUSTER
#undef PACK2
#undef E2

    // f32 partial store: full 64B sector per row per instruction
    float* ob = attnT + ((size_t)qh * BB * HID + (size_t)b * HID + h * CH) * LL;
    *(f32x4*)(ob + (size_t)(r     ) * LL + a0 +      4 * g) = acc00;  // as0, d=r
    *(f32x4*)(ob + (size_t)(16 + r) * LL + a0 +      4 * g) = acc01;  // as0, d=16+r
    *(f32x4*)(ob + (size_t)(r     ) * LL + a0 + 16 + 4 * g) = acc10;  // as1, d=r
    *(f32x4*)(ob + (size_t)(16 + r) * LL + a0 + 16 + 4 * g) = acc11;  // as1, d=16+r
}

// ---------------------------------------------------------------------------
// Kernel 4: out[b,o,l] = BN( w_out @ (sum of 2 f32 partials) + b_out + x )
// ---------------------------------------------------------------------------
__global__ __launch_bounds__(256) void out_kernel(
        const float* __restrict__ attnT, const float* __restrict__ x,
        const float* __restrict__ w_out, const float* __restrict__ b_out,
        const float* __restrict__ bnw, const float* __restrict__ bnb,
        const float* __restrict__ bnm, const float* __restrict__ bnv,
        float* __restrict__ out) {
    __shared__ float wl[8 * 256];
    const int t = threadIdx.x;
    const int l0 = blockIdx.x * 256;
    const int o0 = blockIdx.y * 8;
    const int b  = blockIdx.z;

    const float4* ws = (const float4*)(w_out + (size_t)o0 * HID);
    float4* wd = (float4*)wl;
    #pragma unroll
    for (int r = 0; r < 2; ++r) wd[r * 256 + t] = ws[r * 256 + t];
    __syncthreads();

    float acc[8];
    #pragma unroll
    for (int j = 0; j < 8; ++j) acc[j] = 0.f;

    const size_t PART = (size_t)BB * HID * LL;   // floats per partial
    const float* ap = attnT + (size_t)b * HID * LL + l0 + t;
    for (int i = 0; i < HID; i += 4) {
        const float* p0 = ap + (size_t)(i+0) * LL;
        const float* p1 = ap + (size_t)(i+1) * LL;
        const float* p2 = ap + (size_t)(i+2) * LL;
        const float* p3 = ap + (size_t)(i+3) * LL;
        float a0 = p0[0] + p0[PART];
        float a1 = p1[0] + p1[PART];
        float a2 = p2[0] + p2[PART];
        float a3 = p3[0] + p3[PART];
        #pragma unroll
        for (int j = 0; j < 8; ++j) {
            float4 w4 = *(const float4*)(wl + j * 256 + i);
            acc[j] += w4.x * a0 + w4.y * a1 + w4.z * a2 + w4.w * a3;
        }
    }
    #pragma unroll
    for (int j = 0; j < 8; ++j) {
        const int o = o0 + j;
        const float inv = bnw[o] / sqrtf(bnv[o] + 1e-5f);
        const float sh  = bnb[o] - bnm[o] * inv;
        const size_t idx = ((size_t)b * CIN + o) * LL + l0 + t;
        float val = acc[j] + b_out[o] + x[idx];
        out[idx] = val * inv + sh;
    }
}

// ---------------------------------------------------------------------------
extern "C" void kernel_launch(void* const* d_in, const int* in_sizes, int n_in,
                              void* d_out, int out_size, void* d_ws, size_t ws_size,
                              hipStream_t stream) {
    const float* x      = (const float*)d_in[0];
    const float* w_qkv  = (const float*)d_in[1];
    const float* b_qkv  = (const float*)d_in[2];
    const float* w_out  = (const float*)d_in[3];
    const float* b_out  = (const float*)d_in[4];
    const float* bnw    = (const float*)d_in[5];
    const float* bnb    = (const float*)d_in[6];
    const float* bnm    = (const float*)d_in[7];
    const float* bnv    = (const float*)d_in[8];
    float* out = (float*)d_out;

    const size_t NBH = (size_t)BB * HH;          // 32
    const size_t QKV_ELEMS = NBH * LL * CH;      // 2,097,152 bf16 elems each
    unsigned short* qb    = (unsigned short*)d_ws;
    unsigned short* kb    = qb + QKV_ELEMS;
    unsigned short* vtb   = kb + QKV_ELEMS;
    float* attnT = (float*)(vtb + QKV_ELEMS);    // 2 x 8 MB f32 partials

    qkv_kernel<<<dim3(32, 24, BB), 256, 0, stream>>>(x, w_qkv, b_qkv, qb, kb, vtb);
    denom_mfma<<<dim3(1024), 512, 0, stream>>>(qb, kb, vtb);
    attn_mfma<<<dim3(1024), 256, 0, stream>>>(qb, kb, vtb, attnT);
    out_kernel<<<dim3(8, 16, BB), 256, 0, stream>>>(attnT, x, w_out, b_out,
                                                    bnw, bnb, bnm, bnv, out);
}